// Round 9
// baseline (2870.717 us; speedup 1.0000x reference)
//
#include <hip/hip_runtime.h>
#include <stdint.h>

typedef float f32x4 __attribute__((ext_vector_type(4)));
typedef short s16x8 __attribute__((ext_vector_type(8)));

#define TLEN 4096
#define HID  128
#define NG   4   // 4 batch-groups of 16 (B = 64)
#define KSCALE 2.8853900817779268f   // 2*log2(e), folded into W_x, W_h, bias

static __device__ __forceinline__ float asf(uint32_t u) {
    union { uint32_t u; float f; } v; v.u = u; return v.f;
}
static __device__ __forceinline__ uint32_t cvtpk(float lo, float hi) {
    uint32_t r;
    asm("v_cvt_pk_bf16_f32 %0, %1, %2" : "=v"(r) : "v"(lo), "v"(hi));
    return r;
}
static __device__ __forceinline__ void splitbf(float v, unsigned short& hi, unsigned short& lo) {
    uint32_t p = cvtpk(v, 0.f);
    hi = (unsigned short)(p & 0xFFFFu);
    float r = v - asf((uint32_t)hi << 16);
    uint32_t q = cvtpk(r, 0.f);
    lo = (unsigned short)(q & 0xFFFFu);
}

// Row permutation: logical tile row r of wave w=(wv=w>>1, d=w&1) -> hidden idx
//   G = 32*wv + 4*d + 8*(r>>2) + (r&3)
// MFMA C-layout (col=lane&15, row=(lane>>4)*4+j) packed via cvt_pk is then
// exactly B-fragment content: chunk kk=wv, u32 q∈{2d,2d+1} holds rows
// 32kk+8lg+{2q,2q+1} (lo16=even row, hi16=odd row), col=lane.
//
// rnn_rec LDS layout (per parity, 8 KiB): chunk kk HI block @ kk*1024,
// LO block @ 4096+kk*1024. Slot for lane l is 16 B @ 16*l. Reader lane l:
// ds_read_b128 @ kk*1024 + 16*l — 64 unique contiguous addresses (1 KiB),
// zero read conflicts. Writer wave (wv,d) lane l: ds_write_b64 of
// {q=2d,q=2d+1} @ wv*1024 + 16*l + 8*d — tiles [0,8K) exactly once.
//
// ROUND-9 (single lever vs r6): global stores batched — hv stashed in
// obuf[8] registers, flushed once per 8-step group AFTER the inner loop, so
// the __syncthreads vmcnt(0) drain never waits on a just-issued store-ack
// (the flush has a full step (~1270 cy) to retire before the next group's
// first barrier). Read block / MFMA order / tanh / pack / LDS writes /
// __syncthreads are byte-for-byte r6. Arithmetic bit-identical.
// (r7 tested this bundled with a read/MFMA hand-interleave and regressed;
// MfmaUtil drop attributed the damage to the interleave — this isolates
// the store-batching cell.)

// ---------------- Phase 1: pre = (X @ W_x + bias) * 2log2e, permuted layout
__global__ __launch_bounds__(512) void pre_gemm(
        const float* __restrict__ X, const float* __restrict__ W,
        const float* __restrict__ bias, float* preB, int wsOK) {
    const int tid = threadIdx.x;
    const int w  = tid >> 6;      // 0..7 -> (wv = w>>1, d = w&1)
    const int l  = tid & 63;
    const int lg = l >> 4;
    const int lc = l & 15;
    const int g  = blockIdx.x & (NG - 1);
    const int t0 = (blockIdx.x >> 2) << 4;   // 16 timesteps per WG

    const int wv = w >> 1, dd = w & 1;
    const int GA = 32*wv + 4*dd + 8*(lc>>2) + (lc&3);  // A-row (lane lc) global col
    const int Gc = 32*wv + 4*dd + 8*lg;                // C-row base (this lane)

    // A = W_x^T (scaled) split hi/lo: A[r=lc][k], k = 32kk+8lg+j
    s16x8 ahi[4], alo[4];
#pragma unroll
    for (int kk = 0; kk < 4; ++kk) {
        union { s16x8 v; unsigned short u[8]; } Ah, Al;
#pragma unroll
        for (int j = 0; j < 8; ++j) {
            const int k = 32*kk + 8*lg + j;
            splitbf(W[k*HID + GA] * KSCALE, Ah.u[j], Al.u[j]);
        }
        ahi[kk] = Ah.v; alo[kk] = Al.v;
    }
    f32x4 cb;
    {
        const float4 bv = *(const float4*)(bias + Gc);
        cb[0] = bv.x*KSCALE; cb[1] = bv.y*KSCALE;
        cb[2] = bv.z*KSCALE; cb[3] = bv.w*KSCALE;
    }
    const int b = g*16 + lc;
    const float* xp = X + ((size_t)b*TLEN + t0)*HID + 8*lg;
    float* pp; size_t ST;
    if (wsOK) { pp = preB + ((size_t)g*TLEN + t0)*2048 + w*256 + l*4; ST = 2048; }
    else      { pp = preB + ((size_t)b*TLEN + t0)*HID + Gc;           ST = HID;  }

    for (int tt = 0; tt < 16; ++tt) {
        f32x4 c1 = cb;
        f32x4 c2 = {0.f,0.f,0.f,0.f};
        f32x4 c3 = {0.f,0.f,0.f,0.f};
#pragma unroll
        for (int kk = 0; kk < 4; ++kk) {
            const float4 f0 = *(const float4*)(xp + 32*kk);
            const float4 f1 = *(const float4*)(xp + 32*kk + 4);
            const uint32_t p01 = cvtpk(f0.x, f0.y), p23 = cvtpk(f0.z, f0.w);
            const uint32_t p45 = cvtpk(f1.x, f1.y), p67 = cvtpk(f1.z, f1.w);
            const float r0 = f0.x - asf(p01 << 16), r1 = f0.y - asf(p01 & 0xFFFF0000u);
            const float r2 = f0.z - asf(p23 << 16), r3 = f0.w - asf(p23 & 0xFFFF0000u);
            const float r4 = f1.x - asf(p45 << 16), r5 = f1.y - asf(p45 & 0xFFFF0000u);
            const float r6 = f1.z - asf(p67 << 16), r7 = f1.w - asf(p67 & 0xFFFF0000u);
            union { s16x8 v; uint32_t u[4]; } BH, BL;
            BH.u[0] = p01; BH.u[1] = p23; BH.u[2] = p45; BH.u[3] = p67;
            BL.u[0] = cvtpk(r0, r1); BL.u[1] = cvtpk(r2, r3);
            BL.u[2] = cvtpk(r4, r5); BL.u[3] = cvtpk(r6, r7);
            c1 = __builtin_amdgcn_mfma_f32_16x16x32_bf16(ahi[kk], BH.v, c1, 0, 0, 0);
            c2 = __builtin_amdgcn_mfma_f32_16x16x32_bf16(ahi[kk], BL.v, c2, 0, 0, 0);
            c3 = __builtin_amdgcn_mfma_f32_16x16x32_bf16(alo[kk], BH.v, c3, 0, 0, 0);
        }
        f32x4 c;
        c[0] = c1[0]+c2[0]+c3[0]; c[1] = c1[1]+c2[1]+c3[1];
        c[2] = c1[2]+c2[2]+c3[2]; c[3] = c1[3]+c2[3]+c3[3];
        *(f32x4*)pp = c;
        pp += ST;
        xp += HID;
    }
}

// ---------------- Phase 2: recurrence. 4 WGs (16 batches each), 8 waves/WG
// (2/SIMD). r6 schedule + layout; only the global-store batching differs.
template<int WS>
__global__ __launch_bounds__(512) void rnn_rec(
        const float* preB, const float* __restrict__ W, float* out) {
    const int tid = threadIdx.x;
    const int l   = tid & 63;
    const int lg  = l >> 4;
    const int lc  = l & 15;
    const int w8  = tid >> 6;                                   // 0..7
    const int wv  = __builtin_amdgcn_readfirstlane(w8 >> 1);    // chunk
    const int d   = __builtin_amdgcn_readfirstlane(w8 & 1);     // half
    const int g   = blockIdx.x;                                 // 0..3

    __shared__ uint4 ldsb[1024];   // 16 KiB: 2 parity x (HI 4K | LO 4K)
    char* hb = (char*)ldsb;
    {
        uint32_t* z = (uint32_t*)ldsb;
#pragma unroll
        for (int p = 0; p < 8; ++p) z[tid + 512*p] = 0u;   // h(-1) packs = 0
    }

    // A = W_h^T (scaled) split hi/lo, permuted rows for this wave's tile
    s16x8 ahi[4], alo[4];
    const int GA = 32*wv + 4*d + 8*(lc>>2) + (lc&3);
#pragma unroll
    for (int kk = 0; kk < 4; ++kk) {
        union { s16x8 v; unsigned short u[8]; } Ah, Al;
#pragma unroll
        for (int j = 0; j < 8; ++j) {
            const int k = 32*kk + 8*lg + j;
            splitbf(W[(size_t)(HID + k)*HID + GA] * KSCALE, Ah.u[j], Al.u[j]);
        }
        ahi[kk] = Ah.v; alo[kk] = Al.v;
    }

    const int Gc    = 32*wv + 4*d + 8*lg;        // this lane's 4 output rows
    const int slot  = 16*l;                      // read slot (16 B per lane)
    const int wslot = wv*1024 + slot + 8*d;      // hi write slot (lo at +4096)

    // pre pointer (phase-1 layout matches this wave's C tile lane-for-lane)
    const float* pb; int PST;
    if (WS) { pb = preB + (size_t)g*TLEN*2048 + w8*256 + l*4;   PST = 2048; }
    else    { pb = preB + ((size_t)(g*16+lc)*TLEN)*HID + Gc;    PST = HID;  }

    float* pot = out + ((size_t)(g*16+lc)*TLEN)*HID + Gc;
    const size_t OFF2 = (size_t)(64 - (g*16+lc))*TLEN*HID;  // out[-1:] slot
    const bool gtail = (g == NG-1);                          // block-uniform

    f32x4 pf[8];
#pragma unroll
    for (int u = 0; u < 8; ++u) pf[u] = *(const f32x4*)(pb + (size_t)u*PST);

    __syncthreads();   // zero-init visible

    for (int tb = 0; tb < TLEN; tb += 8) {
        float4 obuf[8];
#pragma unroll
        for (int u = 0; u < 8; ++u) {
            const int t = tb + u;
            int tn = t + 8; if (tn > TLEN-1) tn = TLEN-1;   // clamped tail
            const f32x4 nf = *(const f32x4*)(pb + (size_t)tn*PST);

            const char* rb = hb + ((u & 1) ^ 1) * 8192;   // packs(t-1)
            char*       wb = hb + (u & 1) * 8192;         // packs(t)

            // B fragments: 8 ds_read_b128, unique contiguous, conflict-free
            union F { s16x8 v; };
            F BH[4], BL[4];
#pragma unroll
            for (int kk = 0; kk < 4; ++kk) {
                BH[kk].v = *(const s16x8*)(rb + kk*1024 + slot);
                BL[kk].v = *(const s16x8*)(rb + 4096 + kk*1024 + slot);
            }

            f32x4 c1 = pf[u]; pf[u] = nf;
            f32x4 c2 = {0.f,0.f,0.f,0.f};
            f32x4 c3 = {0.f,0.f,0.f,0.f};
#pragma unroll
            for (int kk = 0; kk < 4; ++kk) {
                c1 = __builtin_amdgcn_mfma_f32_16x16x32_bf16(ahi[kk], BH[kk].v, c1, 0,0,0);
                c2 = __builtin_amdgcn_mfma_f32_16x16x32_bf16(ahi[kk], BL[kk].v, c2, 0,0,0);
                c3 = __builtin_amdgcn_mfma_f32_16x16x32_bf16(alo[kk], BH[kk].v, c3, 0,0,0);
            }

            // h = tanh(s / (2log2e)) = 1 - 2/(exp2(s)+1)   (scale pre-folded)
            const float h0 = 1.f - 2.f * __builtin_amdgcn_rcpf(1.f + __builtin_amdgcn_exp2f(c1[0]+c2[0]+c3[0]));
            const float h1 = 1.f - 2.f * __builtin_amdgcn_rcpf(1.f + __builtin_amdgcn_exp2f(c1[1]+c2[1]+c3[1]));
            const float h2 = 1.f - 2.f * __builtin_amdgcn_rcpf(1.f + __builtin_amdgcn_exp2f(c1[2]+c2[2]+c3[2]));
            const float h3 = 1.f - 2.f * __builtin_amdgcn_rcpf(1.f + __builtin_amdgcn_exp2f(c1[3]+c2[3]+c3[3]));

            // stash output in regs; flush once per 8 steps (no store-ack
            // exposure at this step's vmcnt(0) barrier drain)
            float4 hv; hv.x = h0; hv.y = h1; hv.z = h2; hv.w = h3;
            obuf[u] = hv;

            // pack h -> bf16 hi/lo pair; C layout == B layout (own q-pair)
            const uint32_t xa = cvtpk(h0, h1), xb = cvtpk(h2, h3);
            const float l0 = h0 - asf(xa << 16), l1 = h1 - asf(xa & 0xFFFF0000u);
            const float l2 = h2 - asf(xb << 16), l3 = h3 - asf(xb & 0xFFFF0000u);
            uint2 wh; wh.x = xa; wh.y = xb;
            uint2 wl; wl.x = cvtpk(l0, l1); wl.y = cvtpk(l2, l3);
            *(uint2*)(wb + wslot)        = wh;
            *(uint2*)(wb + 4096 + wslot) = wl;

            __syncthreads();   // full drain each step (fast family: r0/r6)
        }

        // batched flush: retires during the next tb-group's first step.
        // fb path safe: lane writes only its own (batch,row) slice, and its
        // pre(t') reads (t' >= tb+8) are disjoint from rows tb..tb+7; same
        // lane both sides -> program order.
#pragma unroll
        for (int i = 0; i < 8; ++i)
            *(float4*)(pot + (size_t)i*HID) = obuf[i];
        if (gtail) {
            if (lc == 15) {
#pragma unroll
                for (int i = 0; i < 8; ++i)
                    *(float4*)(pot + OFF2 + (size_t)i*HID) = obuf[i];
            }
        }
        pot += 8*HID;
    }
}

extern "C" void kernel_launch(void* const* d_in, const int* in_sizes, int n_in,
                              void* d_out, int out_size, void* d_ws, size_t ws_size,
                              hipStream_t stream) {
    const float* X    = (const float*)d_in[0];
    const float* Wt   = (const float*)d_in[1];
    const float* bias = (const float*)d_in[2];
    float* out = (float*)d_out;

    const size_t need = (size_t)NG * TLEN * 2048 * sizeof(float);   // 128 MB
    if (ws_size >= need) {
        float* preB = (float*)d_ws;
        pre_gemm<<<dim3(NG * 256), dim3(512), 0, stream>>>(X, Wt, bias, preB, 1);
        rnn_rec<1><<<dim3(NG), dim3(512), 0, stream>>>(preB, Wt, out);
    } else {
        // pre stored inside d_out rows; batched flush overwrites rows
        // tb..tb+7 after they are last read — same lane both sides,
        // program order + per-step __syncthreads.
        pre_gemm<<<dim3(NG * 256), dim3(512), 0, stream>>>(X, Wt, bias, out, 0);
        rnn_rec<0><<<dim3(NG), dim3(512), 0, stream>>>(out, Wt, out);
    }
}

// Round 10
// 2290.152 us; speedup vs baseline: 1.2535x; 1.2535x over previous
//
#include <hip/hip_runtime.h>
#include <stdint.h>

typedef float f32x4 __attribute__((ext_vector_type(4)));
typedef short s16x8 __attribute__((ext_vector_type(8)));

#define TLEN 4096
#define HID  128
#define NG   4   // 4 batch-groups of 16 (B = 64)
#define KSCALE 2.8853900817779268f   // 2*log2(e), folded into W_x, W_h, bias

static __device__ __forceinline__ float asf(uint32_t u) {
    union { uint32_t u; float f; } v; v.u = u; return v.f;
}
static __device__ __forceinline__ uint32_t cvtpk(float lo, float hi) {
    uint32_t r;
    asm("v_cvt_pk_bf16_f32 %0, %1, %2" : "=v"(r) : "v"(lo), "v"(hi));
    return r;
}
static __device__ __forceinline__ void splitbf(float v, unsigned short& hi, unsigned short& lo) {
    uint32_t p = cvtpk(v, 0.f);
    hi = (unsigned short)(p & 0xFFFFu);
    float r = v - asf((uint32_t)hi << 16);
    uint32_t q = cvtpk(r, 0.f);
    lo = (unsigned short)(q & 0xFFFFu);
}

// Row permutation: logical tile row r of wave w=(wv=w>>1, d=w&1) -> hidden idx
//   G = 32*wv + 4*d + 8*(r>>2) + (r&3)
// MFMA C-layout (col=lane&15, row=(lane>>4)*4+j) packed via cvt_pk is then
// exactly B-fragment content: chunk kk=wv, u32 q∈{2d,2d+1} holds rows
// 32kk+8lg+{2q,2q+1} (lo16=even row, hi16=odd row), col=lane.
//
// rnn_rec LDS layout (per parity, 8 KiB): chunk kk HI block @ kk*1024,
// LO block @ 4096+kk*1024. Slot for lane l is 16 B @ 16*l. Reader lane l:
// ds_read_b128 @ kk*1024 + 16*l — 64 unique contiguous addresses (1 KiB),
// zero read conflicts. Writer wave (wv,d) lane l: ds_write_b64 of
// {q=2d,q=2d+1} @ wv*1024 + 16*l + 8*d — tiles [0,8K) exactly once.
//
// ROUND-10 (single lever vs r6): lgkm-only barrier in the workspace path.
// __syncthreads' vmcnt(0) drain waits each step on the just-issued hv store
// (~100-300 cy exposed) and the nf HBM-load tail. Cross-wave data flows only
// through LDS -> s_waitcnt lgkmcnt(0) + s_barrier is sufficient; all global
// accesses are lane-private (per-wave in-order vmem issue orders same-lane
// accesses). Everything else is byte-for-byte r6. Arithmetic bit-identical.
// (r1/r2/r3/r5 used this barrier but each bundled an independently-proven
// confounder; this isolates the barrier cell on the fast-family base.)

// ---------------- Phase 1: pre = (X @ W_x + bias) * 2log2e, permuted layout
__global__ __launch_bounds__(512) void pre_gemm(
        const float* __restrict__ X, const float* __restrict__ W,
        const float* __restrict__ bias, float* preB, int wsOK) {
    const int tid = threadIdx.x;
    const int w  = tid >> 6;      // 0..7 -> (wv = w>>1, d = w&1)
    const int l  = tid & 63;
    const int lg = l >> 4;
    const int lc = l & 15;
    const int g  = blockIdx.x & (NG - 1);
    const int t0 = (blockIdx.x >> 2) << 4;   // 16 timesteps per WG

    const int wv = w >> 1, dd = w & 1;
    const int GA = 32*wv + 4*dd + 8*(lc>>2) + (lc&3);  // A-row (lane lc) global col
    const int Gc = 32*wv + 4*dd + 8*lg;                // C-row base (this lane)

    // A = W_x^T (scaled) split hi/lo: A[r=lc][k], k = 32kk+8lg+j
    s16x8 ahi[4], alo[4];
#pragma unroll
    for (int kk = 0; kk < 4; ++kk) {
        union { s16x8 v; unsigned short u[8]; } Ah, Al;
#pragma unroll
        for (int j = 0; j < 8; ++j) {
            const int k = 32*kk + 8*lg + j;
            splitbf(W[k*HID + GA] * KSCALE, Ah.u[j], Al.u[j]);
        }
        ahi[kk] = Ah.v; alo[kk] = Al.v;
    }
    f32x4 cb;
    {
        const float4 bv = *(const float4*)(bias + Gc);
        cb[0] = bv.x*KSCALE; cb[1] = bv.y*KSCALE;
        cb[2] = bv.z*KSCALE; cb[3] = bv.w*KSCALE;
    }
    const int b = g*16 + lc;
    const float* xp = X + ((size_t)b*TLEN + t0)*HID + 8*lg;
    float* pp; size_t ST;
    if (wsOK) { pp = preB + ((size_t)g*TLEN + t0)*2048 + w*256 + l*4; ST = 2048; }
    else      { pp = preB + ((size_t)b*TLEN + t0)*HID + Gc;           ST = HID;  }

    for (int tt = 0; tt < 16; ++tt) {
        f32x4 c1 = cb;
        f32x4 c2 = {0.f,0.f,0.f,0.f};
        f32x4 c3 = {0.f,0.f,0.f,0.f};
#pragma unroll
        for (int kk = 0; kk < 4; ++kk) {
            const float4 f0 = *(const float4*)(xp + 32*kk);
            const float4 f1 = *(const float4*)(xp + 32*kk + 4);
            const uint32_t p01 = cvtpk(f0.x, f0.y), p23 = cvtpk(f0.z, f0.w);
            const uint32_t p45 = cvtpk(f1.x, f1.y), p67 = cvtpk(f1.z, f1.w);
            const float r0 = f0.x - asf(p01 << 16), r1 = f0.y - asf(p01 & 0xFFFF0000u);
            const float r2 = f0.z - asf(p23 << 16), r3 = f0.w - asf(p23 & 0xFFFF0000u);
            const float r4 = f1.x - asf(p45 << 16), r5 = f1.y - asf(p45 & 0xFFFF0000u);
            const float r6 = f1.z - asf(p67 << 16), r7 = f1.w - asf(p67 & 0xFFFF0000u);
            union { s16x8 v; uint32_t u[4]; } BH, BL;
            BH.u[0] = p01; BH.u[1] = p23; BH.u[2] = p45; BH.u[3] = p67;
            BL.u[0] = cvtpk(r0, r1); BL.u[1] = cvtpk(r2, r3);
            BL.u[2] = cvtpk(r4, r5); BL.u[3] = cvtpk(r6, r7);
            c1 = __builtin_amdgcn_mfma_f32_16x16x32_bf16(ahi[kk], BH.v, c1, 0, 0, 0);
            c2 = __builtin_amdgcn_mfma_f32_16x16x32_bf16(ahi[kk], BL.v, c2, 0, 0, 0);
            c3 = __builtin_amdgcn_mfma_f32_16x16x32_bf16(alo[kk], BH.v, c3, 0, 0, 0);
        }
        f32x4 c;
        c[0] = c1[0]+c2[0]+c3[0]; c[1] = c1[1]+c2[1]+c3[1];
        c[2] = c1[2]+c2[2]+c3[2]; c[3] = c1[3]+c2[3]+c3[3];
        *(f32x4*)pp = c;
        pp += ST;
        xp += HID;
    }
}

// ---------------- Phase 2: recurrence. 4 WGs (16 batches each), 8 waves/WG
// (2/SIMD). r6 schedule + layout; only the barrier differs (WS=1 path).
template<int WS>
__global__ __launch_bounds__(512) void rnn_rec(
        const float* preB, const float* __restrict__ W, float* out) {
    const int tid = threadIdx.x;
    const int l   = tid & 63;
    const int lg  = l >> 4;
    const int lc  = l & 15;
    const int w8  = tid >> 6;                                   // 0..7
    const int wv  = __builtin_amdgcn_readfirstlane(w8 >> 1);    // chunk
    const int d   = __builtin_amdgcn_readfirstlane(w8 & 1);     // half
    const int g   = blockIdx.x;                                 // 0..3

    __shared__ uint4 ldsb[1024];   // 16 KiB: 2 parity x (HI 4K | LO 4K)
    char* hb = (char*)ldsb;
    {
        uint32_t* z = (uint32_t*)ldsb;
#pragma unroll
        for (int p = 0; p < 8; ++p) z[tid + 512*p] = 0u;   // h(-1) packs = 0
    }

    // A = W_h^T (scaled) split hi/lo, permuted rows for this wave's tile
    s16x8 ahi[4], alo[4];
    const int GA = 32*wv + 4*d + 8*(lc>>2) + (lc&3);
#pragma unroll
    for (int kk = 0; kk < 4; ++kk) {
        union { s16x8 v; unsigned short u[8]; } Ah, Al;
#pragma unroll
        for (int j = 0; j < 8; ++j) {
            const int k = 32*kk + 8*lg + j;
            splitbf(W[(size_t)(HID + k)*HID + GA] * KSCALE, Ah.u[j], Al.u[j]);
        }
        ahi[kk] = Ah.v; alo[kk] = Al.v;
    }

    const int Gc    = 32*wv + 4*d + 8*lg;        // this lane's 4 output rows
    const int slot  = 16*l;                      // read slot (16 B per lane)
    const int wslot = wv*1024 + slot + 8*d;      // hi write slot (lo at +4096)

    // pre pointer (phase-1 layout matches this wave's C tile lane-for-lane)
    const float* pb; int PST;
    if (WS) { pb = preB + (size_t)g*TLEN*2048 + w8*256 + l*4;   PST = 2048; }
    else    { pb = preB + ((size_t)(g*16+lc)*TLEN)*HID + Gc;    PST = HID;  }

    float* pot = out + ((size_t)(g*16+lc)*TLEN)*HID + Gc;
    const size_t OFF2 = (size_t)(64 - (g*16+lc))*TLEN*HID;  // out[-1:] slot
    const bool gtail = (g == NG-1);                          // block-uniform

    f32x4 pf[8];
#pragma unroll
    for (int u = 0; u < 8; ++u) pf[u] = *(const f32x4*)(pb + (size_t)u*PST);

    __syncthreads();   // zero-init visible

    for (int tb = 0; tb < TLEN; tb += 8) {
#pragma unroll
        for (int u = 0; u < 8; ++u) {
            const int t = tb + u;
            int tn = t + 8; if (tn > TLEN-1) tn = TLEN-1;   // clamped tail
            const f32x4 nf = *(const f32x4*)(pb + (size_t)tn*PST);

            const char* rb = hb + ((u & 1) ^ 1) * 8192;   // packs(t-1)
            char*       wb = hb + (u & 1) * 8192;         // packs(t)

            // B fragments: 8 ds_read_b128, unique contiguous, conflict-free
            union F { s16x8 v; };
            F BH[4], BL[4];
#pragma unroll
            for (int kk = 0; kk < 4; ++kk) {
                BH[kk].v = *(const s16x8*)(rb + kk*1024 + slot);
                BL[kk].v = *(const s16x8*)(rb + 4096 + kk*1024 + slot);
            }

            f32x4 c1 = pf[u]; pf[u] = nf;
            f32x4 c2 = {0.f,0.f,0.f,0.f};
            f32x4 c3 = {0.f,0.f,0.f,0.f};
#pragma unroll
            for (int kk = 0; kk < 4; ++kk) {
                c1 = __builtin_amdgcn_mfma_f32_16x16x32_bf16(ahi[kk], BH[kk].v, c1, 0,0,0);
                c2 = __builtin_amdgcn_mfma_f32_16x16x32_bf16(ahi[kk], BL[kk].v, c2, 0,0,0);
                c3 = __builtin_amdgcn_mfma_f32_16x16x32_bf16(alo[kk], BH[kk].v, c3, 0,0,0);
            }

            // h = tanh(s / (2log2e)) = 1 - 2/(exp2(s)+1)   (scale pre-folded)
            const float h0 = 1.f - 2.f * __builtin_amdgcn_rcpf(1.f + __builtin_amdgcn_exp2f(c1[0]+c2[0]+c3[0]));
            const float h1 = 1.f - 2.f * __builtin_amdgcn_rcpf(1.f + __builtin_amdgcn_exp2f(c1[1]+c2[1]+c3[1]));
            const float h2 = 1.f - 2.f * __builtin_amdgcn_rcpf(1.f + __builtin_amdgcn_exp2f(c1[2]+c2[2]+c3[2]));
            const float h3 = 1.f - 2.f * __builtin_amdgcn_rcpf(1.f + __builtin_amdgcn_exp2f(c1[3]+c2[3]+c3[3]));

            // global stores (r6 placement: before pack)
            float4 hv; hv.x = h0; hv.y = h1; hv.z = h2; hv.w = h3;
            *(float4*)pot = hv;
            if (gtail) {                       // uniform: 3 of 4 blocks skip
                if (lc == 15) *(float4*)(pot + OFF2) = hv;
            }
            pot += HID;

            // pack h -> bf16 hi/lo pair; C layout == B layout (own q-pair)
            const uint32_t xa = cvtpk(h0, h1), xb = cvtpk(h2, h3);
            const float l0 = h0 - asf(xa << 16), l1 = h1 - asf(xa & 0xFFFF0000u);
            const float l2 = h2 - asf(xb << 16), l3 = h3 - asf(xb & 0xFFFF0000u);
            uint2 wh; wh.x = xa; wh.y = xb;
            uint2 wl; wl.x = cvtpk(l0, l1); wl.y = cvtpk(l2, l3);
            *(uint2*)(wb + wslot)        = wh;
            *(uint2*)(wb + 4096 + wslot) = wl;

            if (WS) {
                // LDS-only drain + barrier: hv store and nf load stay in
                // flight across the barrier (all global accesses lane-private)
                asm volatile("s_waitcnt lgkmcnt(0)" ::: "memory");
                __builtin_amdgcn_s_barrier();
            } else {
                __syncthreads();   // fb path aliases pre into out: full drain
            }
        }
    }
}

extern "C" void kernel_launch(void* const* d_in, const int* in_sizes, int n_in,
                              void* d_out, int out_size, void* d_ws, size_t ws_size,
                              hipStream_t stream) {
    const float* X    = (const float*)d_in[0];
    const float* Wt   = (const float*)d_in[1];
    const float* bias = (const float*)d_in[2];
    float* out = (float*)d_out;

    const size_t need = (size_t)NG * TLEN * 2048 * sizeof(float);   // 128 MB
    if (ws_size >= need) {
        float* preB = (float*)d_ws;
        pre_gemm<<<dim3(NG * 256), dim3(512), 0, stream>>>(X, Wt, bias, preB, 1);
        rnn_rec<1><<<dim3(NG), dim3(512), 0, stream>>>(preB, Wt, out);
    } else {
        // pre stored inside d_out rows; overwritten at step t, read at t-8 —
        // each lane reads/writes only its own (batch,row) slice, ordered by
        // the per-step full __syncthreads.
        pre_gemm<<<dim3(NG * 256), dim3(512), 0, stream>>>(X, Wt, bias, out, 0);
        rnn_rec<0><<<dim3(NG), dim3(512), 0, stream>>>(out, Wt, out);
    }
}